// Round 14
// baseline (946.021 us; speedup 1.0000x reference)
//
#include <hip/hip_runtime.h>

// ConvLSTM cell, MI355X. Implicit-GEMM over concat(x,h) channels, bf16 MFMA
// 32x32x16, fused in-register LSTM epilogue.
// R14: barrier-free streaming main kernel — NO LDS. B-frags read directly
// from linear padded planes in global (L1/L2-resident; every line fully
// consumed within a phase-pair), dist-2 3-slot rotation for both A and B,
// all per-phase offsets literal-folded (SGPR base + 32-bit voffset + imm).
// No __syncthreads in the loop: waves self-skew (m114 overlap), setprio
// gets role-diversity. Wt placed FIRST in ws so last-ibk dummy prefetch
// overrun lands in the xh region (valid memory).

typedef __bf16 bf16x8 __attribute__((ext_vector_type(8)));
typedef float f32x16 __attribute__((ext_vector_type(16)));

#define PLANE_B  20736u                 // 324 positions * 64 B (18x18x32 bf16)
#define WT_BYTES 9441280u               // 9,437,184 + 4096 align slack
#define OUT_HALF 16777216u              // B*CH*S

// ---------------------------------------------------------------------------
// P1a: x,h (NCHW fp32) -> padded LINEAR bf16 planes (zero border, no swizzle).
// plane(b,ibk)[p][c] at byte p*64 + c*2, p = (y+1)*18 + (x+1) for interior.
__global__ __launch_bounds__(256) void xh_transform(
    const float* __restrict__ x, const float* __restrict__ hh,
    unsigned char* __restrict__ xh)
{
    int blk = blockIdx.x;              // b*16 + ibk
    int b = blk >> 4, ibk = blk & 15;
    const float* src = (ibk < 8) ? (x  + ((size_t)(b*256 + ibk*32)) * 256)
                                 : (hh + ((size_t)(b*256 + (ibk-8)*32)) * 256);
    int t = threadIdx.x;               // t == spatial s
    uint32_t w[16];
#pragma unroll
    for (int i = 0; i < 16; ++i) {
        __bf16 lo = (__bf16)src[(size_t)(2*i  )*256 + t];
        __bf16 hi = (__bf16)src[(size_t)(2*i+1)*256 + t];
        w[i] = (uint32_t)__builtin_bit_cast(unsigned short, lo)
             | ((uint32_t)__builtin_bit_cast(unsigned short, hi) << 16);
    }
    unsigned char* plane = xh + (size_t)blk * PLANE_B;
    int p = ((t >> 4) + 1)*18 + (t & 15) + 1;      // interior position
    uint4* dst = (uint4*)(plane + (uint32_t)p*64u);
    dst[0] = uint4{w[0],  w[1],  w[2],  w[3]};
    dst[1] = uint4{w[4],  w[5],  w[6],  w[7]};
    dst[2] = uint4{w[8],  w[9],  w[10], w[11]};
    dst[3] = uint4{w[12], w[13], w[14], w[15]};
    // zero the 68 border positions (rows 0,17; cols 0,17)
    if (t < 68) {
        int pb;
        if      (t < 18) pb = t;                   // row 0
        else if (t < 36) pb = 17*18 + (t - 18);    // row 17
        else if (t < 52) pb = (t - 35)*18;         // rows 1..16, col 0
        else             pb = (t - 51)*18 + 17;    // rows 1..16, col 17
        uint4 z{0u,0u,0u,0u};
        uint4* zd = (uint4*)(plane + (uint32_t)pb*64u);
        zd[0] = z; zd[1] = z; zd[2] = z; zd[3] = z;
    }
}

// ---------------------------------------------------------------------------
// P1b: Wx,Wh (OIHW fp32) -> Wt bf16 in A-fragment order.
// chunk = ((cbnh*16 + ibk)*9 + pos)*4 + half*2 + f ; 64 lanes x 8 bf16 each.
__global__ __launch_bounds__(256) void w_transform(
    const float* __restrict__ Wx, const float* __restrict__ Wh,
    __bf16* __restrict__ Wt)
{
    int idx  = blockIdx.x * 256 + threadIdx.x;   // 589824 total
    int lane = idx & 63;
    int chunk = idx >> 6;                        // 9216 chunks
    int f     = chunk & 1;
    int half  = (chunk >> 1) & 1;
    int pos   = (chunk >> 2) % 9;                // ky*3+kx
    int rest  = (chunk >> 2) / 9;                // 0..255
    int ibk   = rest & 15;
    int cbnh  = rest >> 4;
    int nh = cbnh & 1, cb = cbnh >> 1;
    int row = lane & 31, hl = lane >> 5;
    int gate = row & 3, ch8 = row >> 2;
    int oc  = gate*256 + cb*32 + (nh*2 + f)*8 + ch8;
    int ic0 = ibk*32 + half*16 + hl*8;
    bf16x8 v;
#pragma unroll
    for (int j = 0; j < 8; ++j) {
        int ic = ic0 + j;
        float w = (ic < 256) ? Wx[((size_t)oc*256 + ic      )*9 + pos]
                             : Wh[((size_t)oc*256 + (ic-256))*9 + pos];
        v[j] = (__bf16)w;
    }
    *(bf16x8*)(Wt + (size_t)chunk*512 + (size_t)lane*8) = v;
}

// ---------------------------------------------------------------------------
// Main. Block = (b, nh, cb): 256m x 64oc'. 4 waves, each 64m x 64oc:
// acc[2][2] f32x16 = 64 AGPR. No LDS, no barriers. 288 global phases,
// A and B dist-2 in 3-slot rotations; setprio around each 4-MFMA cluster.
__global__ __launch_bounds__(256, 2) void convlstm_main(
    const unsigned char* __restrict__ xh, const unsigned char* __restrict__ Wtb,
    const float* __restrict__ bh,  const float* __restrict__ cin,
    const float* __restrict__ Wci, const float* __restrict__ Wcf,
    const float* __restrict__ Wco, float* __restrict__ out)
{
    int bid = blockIdx.x;               // b*16 + nh*8 + cb
    int cb  = bid & 7;
    int nh  = (bid >> 3) & 1;
    int b   = bid >> 4;
    int tid = threadIdx.x;
    int lane = tid & 63, wv = tid >> 6;
    int l31 = lane & 31, hl = lane >> 5;

    // accumulators init with bias bh[oc]
    f32x16 acc[2][2];
#pragma unroll
    for (int f = 0; f < 2; ++f) {
        int fg = nh*2 + f;
        f32x16 v;
#pragma unroll
        for (int r = 0; r < 16; ++r) {
            int gate = r & 3, q = r >> 2;
            v[r] = bh[gate*256 + cb*32 + fg*8 + 2*q + hl];
        }
        acc[0][f] = v; acc[1][f] = v;
    }

    // SGPR bases (block-uniform pointers)
    const unsigned char* planeB = xh  + (size_t)b * (16u * PLANE_B);
    const unsigned char* wbase  = Wtb + (size_t)(cb*2 + nh) * 589824u;

    // 32-bit per-lane voffsets
    int m0 = wv*64 + l31, m1 = m0 + 32;
    uint32_t voffB0 = (uint32_t)(((m0 >> 4)*18 + (m0 & 15))*64 + hl*16);
    uint32_t voffB1 = (uint32_t)(((m1 >> 4)*18 + (m1 & 15))*64 + hl*16);
    uint32_t voffA  = (uint32_t)(lane*16);

    // Prologue: phases 0,1 of ibk 0 into slots 0,1.
    // A chunk (G = global phase, f) at byte G*2048 + f*1024 + lane*16.
    // B read (pos,half) at voffB + d(pos)*64 + half*32, d = (pos/3)*18+pos%3.
    bf16x8 A[3][2], Bb[3][2];
    A[0][0] = *(const bf16x8*)(wbase + voffA + 0);
    A[0][1] = *(const bf16x8*)(wbase + voffA + 1024);
    A[1][0] = *(const bf16x8*)(wbase + voffA + 2048);
    A[1][1] = *(const bf16x8*)(wbase + voffA + 3072);
    Bb[0][0] = *(const bf16x8*)(planeB + voffB0 + 0);
    Bb[0][1] = *(const bf16x8*)(planeB + voffB1 + 0);
    Bb[1][0] = *(const bf16x8*)(planeB + voffB0 + 32);
    Bb[1][1] = *(const bf16x8*)(planeB + voffB1 + 32);

    for (int ibk = 0; ibk < 16; ++ibk) {
#pragma unroll
        for (int p = 0; p < 18; ++p) {
            // advance A offset; after this, voffA = lane*16 + (G_now+1)*2048
            voffA += 2048u;
            // cross to next plane just before the cross-ibk B prefetches
            if (p == 16 && ibk < 15) {
                voffB0 += PLANE_B;
                voffB1 += PLANE_B;
            }
            // prefetch phase p+2 into slot (p+2)%3 (18%3==0: static across ibk)
            {
                const int tp = p + 2;
                const int tl = (tp < 18) ? tp : tp - 18;   // literal
                const uint32_t blit =
                    (uint32_t)(((((tl >> 1) / 3)*18 + ((tl >> 1) % 3))*64)
                               + (tl & 1)*32);
                // A: literal 2048 (+f*1024) past current voffA == phase p+2.
                // At ibk 15, p>=16 this reads past the Wt slice (dummy, never
                // consumed) — lands in xh region (Wt placed first in ws).
                A[(p+2)%3][0] = *(const bf16x8*)(wbase + voffA + 2048u);
                A[(p+2)%3][1] = *(const bf16x8*)(wbase + voffA + 3072u);
                Bb[(p+2)%3][0] = *(const bf16x8*)(planeB + voffB0 + blit);
                Bb[(p+2)%3][1] = *(const bf16x8*)(planeB + voffB1 + blit);
            }
            __builtin_amdgcn_s_setprio(1);
            acc[0][0] = __builtin_amdgcn_mfma_f32_32x32x16_bf16(A[p%3][0], Bb[p%3][0], acc[0][0], 0, 0, 0);
            acc[0][1] = __builtin_amdgcn_mfma_f32_32x32x16_bf16(A[p%3][1], Bb[p%3][0], acc[0][1], 0, 0, 0);
            acc[1][0] = __builtin_amdgcn_mfma_f32_32x32x16_bf16(A[p%3][0], Bb[p%3][1], acc[1][0], 0, 0, 0);
            acc[1][1] = __builtin_amdgcn_mfma_f32_32x32x16_bf16(A[p%3][1], Bb[p%3][1], acc[1][1], 0, 0, 0);
            __builtin_amdgcn_s_setprio(0);
        }
    }

    // fused LSTM epilogue. col = l31 (m), r = 4*q + gate,
    // ch = cb*32 + fg*8 + 2*q + hl.
    float* outh = out;
    float* outc = out + (size_t)OUT_HALF;
    const size_t bOff = (size_t)b * (256*256);
#pragma unroll
    for (int mf = 0; mf < 2; ++mf) {
        int m = wv*64 + mf*32 + l31;
#pragma unroll
        for (int f = 0; f < 2; ++f) {
            int fg = nh*2 + f;
#pragma unroll
            for (int q = 0; q < 4; ++q) {
                int ch = cb*32 + fg*8 + 2*q + hl;
                size_t pidx = (size_t)ch*256 + (size_t)m;
                size_t idx  = bOff + pidx;
                float cv = cin[idx];
                float pi = acc[mf][f][4*q+0];
                float pf = acc[mf][f][4*q+1];
                float pc = acc[mf][f][4*q+2];
                float po = acc[mf][f][4*q+3];
                float it = 1.f/(1.f + __expf(-(pi + Wci[pidx]*cv)));
                float ft = 1.f/(1.f + __expf(-(pf + Wcf[pidx]*cv)));
                float tc = 1.f - 2.f/(1.f + __expf(2.f*pc));
                float ct = ft*cv + it*tc;
                float ot = 1.f/(1.f + __expf(-(po + Wco[pidx]*ct)));
                float th = 1.f - 2.f/(1.f + __expf(2.f*ct));
                outh[idx] = ot*th;
                outc[idx] = ct;
            }
        }
    }
}

// ---------------------------------------------------------------------------
extern "C" void kernel_launch(void* const* d_in, const int* in_sizes, int n_in,
                              void* d_out, int out_size, void* d_ws, size_t ws_size,
                              hipStream_t stream)
{
    const float* x   = (const float*)d_in[0];
    const float* h   = (const float*)d_in[1];
    const float* c   = (const float*)d_in[2];
    const float* Wx  = (const float*)d_in[3];
    const float* Wh  = (const float*)d_in[4];
    const float* bh  = (const float*)d_in[5];
    const float* Wci = (const float*)d_in[6];
    const float* Wcf = (const float*)d_in[7];
    const float* Wco = (const float*)d_in[8];
    float* out = (float*)d_out;

    // Wt FIRST so last-ibk dummy A prefetches (≤ ~6 KB past a slice end)
    // land inside the xh region for the final slice.
    unsigned char* wtb = (unsigned char*)d_ws;       // 9.44 MB (+align)
    unsigned char* xh  = wtb + (size_t)WT_BYTES;     // 84,934,656 B planes

    hipLaunchKernelGGL(xh_transform, dim3(4096), dim3(256), 0, stream, x, h, xh);
    hipLaunchKernelGGL(w_transform,  dim3(2304), dim3(256), 0, stream,
                       Wx, Wh, (__bf16*)wtb);
    hipLaunchKernelGGL(convlstm_main, dim3(4096), dim3(256), 0, stream,
                       xh, wtb, bh, c, Wci, Wcf, Wco, out);
}

// Round 15
// 630.243 us; speedup vs baseline: 1.5010x; 1.5010x over previous
//
#include <hip/hip_runtime.h>

// ConvLSTM cell, MI355X. Implicit-GEMM over concat(x,h) channels, bf16 MFMA
// 32x32x16, fused in-register LSTM epilogue.
// R15: 4-blocks/CU push. Half-K LDS sub-buffers (16ch x 324 pos = 10368 B,
// double-buffered = 20736 B/block), 9 phases per sub-buffer, 32 sub-buffers.
// Register diet: A/B dist-1 ping-pong (16+16), computed B addresses (2 base
// regs), literal A offsets -> target <=64 arch + 64 AGPR = 128 = 4 waves/SIMD.
// Swizzle ^((p&4)<<2); counted vmcnt(4) barrier; PAR-literal sub-buffer pairs.

typedef __bf16 bf16x8 __attribute__((ext_vector_type(8)));
typedef float f32x16 __attribute__((ext_vector_type(16)));

#define SUB_B    10368u                 // 324 positions * 32 B (16 ch bf16)
#define WT_BYTES 9441280u               // 9,437,184 + align slack
#define OUT_HALF 16777216u              // B*CH*S

__device__ inline void gload_lds16(const void* g, void* l) {
    __builtin_amdgcn_global_load_lds(
        (const __attribute__((address_space(1))) void*)g,
        (__attribute__((address_space(3))) void*)l, 16, 0, 0);
}

// ---------------------------------------------------------------------------
// P1a: x,h (NCHW fp32) -> per-(b,ibk) TWO half-K sub-planes (16 ch each),
// packed 10368 B, zero border, swizzled: byte = (p*32 + ofs) ^ ((p&4)<<2).
__global__ __launch_bounds__(256) void xh_transform(
    const float* __restrict__ x, const float* __restrict__ hh,
    unsigned char* __restrict__ xh)
{
    int blk = blockIdx.x;              // b*16 + ibk
    int b = blk >> 4, ibk = blk & 15;
    const float* src = (ibk < 8) ? (x  + ((size_t)(b*256 + ibk*32)) * 256)
                                 : (hh + ((size_t)(b*256 + (ibk-8)*32)) * 256);
    int t = threadIdx.x;               // t == spatial s
    uint32_t w[16];
#pragma unroll
    for (int i = 0; i < 16; ++i) {
        __bf16 lo = (__bf16)src[(size_t)(2*i  )*256 + t];
        __bf16 hi = (__bf16)src[(size_t)(2*i+1)*256 + t];
        w[i] = (uint32_t)__builtin_bit_cast(unsigned short, lo)
             | ((uint32_t)__builtin_bit_cast(unsigned short, hi) << 16);
    }
    int p = ((t >> 4) + 1)*18 + (t & 15) + 1;      // interior position
    uint32_t key  = ((uint32_t)p & 4u) << 2;
    uint32_t base = (uint32_t)p * 32u;
#pragma unroll
    for (int hb = 0; hb < 2; ++hb) {
        unsigned char* sp = xh + (size_t)(blk*2 + hb) * SUB_B;
        *(uint4*)(sp + ((base +  0u) ^ key)) =
            uint4{w[8*hb+0], w[8*hb+1], w[8*hb+2], w[8*hb+3]};
        *(uint4*)(sp + ((base + 16u) ^ key)) =
            uint4{w[8*hb+4], w[8*hb+5], w[8*hb+6], w[8*hb+7]};
    }
    // zero the 68 border positions (rows 0,17; cols 0,17) in both halves
    if (t < 68) {
        int pb;
        if      (t < 18) pb = t;                   // row 0
        else if (t < 36) pb = 17*18 + (t - 18);    // row 17
        else if (t < 52) pb = (t - 35)*18;         // rows 1..16, col 0
        else             pb = (t - 51)*18 + 17;    // rows 1..16, col 17
        uint32_t kb = ((uint32_t)pb & 4u) << 2;
        uint32_t bb = (uint32_t)pb * 32u;
        uint4 z{0u,0u,0u,0u};
#pragma unroll
        for (int hb = 0; hb < 2; ++hb) {
            unsigned char* sp = xh + (size_t)(blk*2 + hb) * SUB_B;
            *(uint4*)(sp + ((bb +  0u) ^ kb)) = z;
            *(uint4*)(sp + ((bb + 16u) ^ kb)) = z;
        }
    }
}

// ---------------------------------------------------------------------------
// P1b: Wx,Wh (OIHW fp32) -> Wt bf16 in A-fragment order.
// chunk = ((((cbnh*16 + ibk)*2 + half)*9 + pos)*2 + f ; 64 lanes x 8 bf16.
__global__ __launch_bounds__(256) void w_transform(
    const float* __restrict__ Wx, const float* __restrict__ Wh,
    __bf16* __restrict__ Wt)
{
    int idx  = blockIdx.x * 256 + threadIdx.x;   // 589824 total
    int lane = idx & 63;
    int chunk = idx >> 6;                        // 9216 chunks
    int f    = chunk & 1;
    int q    = chunk >> 1;
    int pos  = q % 9;
    int r    = q / 9;
    int half = r & 1;
    int ibk  = (r >> 1) & 15;
    int cbnh = r >> 5;
    int nh = cbnh & 1, cb = cbnh >> 1;
    int row = lane & 31, hl = lane >> 5;
    int gate = row & 3, ch8 = row >> 2;
    int oc  = gate*256 + cb*32 + (nh*2 + f)*8 + ch8;
    int ic0 = ibk*32 + half*16 + hl*8;
    bf16x8 v;
#pragma unroll
    for (int j = 0; j < 8; ++j) {
        int ic = ic0 + j;
        float w = (ic < 256) ? Wx[((size_t)oc*256 + ic      )*9 + pos]
                             : Wh[((size_t)oc*256 + (ic-256))*9 + pos];
        v[j] = (__bf16)w;
    }
    *(bf16x8*)(Wt + (size_t)chunk*512 + (size_t)lane*8) = v;
}

// ---------------------------------------------------------------------------
// Main. Block = (b, nh, cb): 256m x 64oc'. 4 waves, each 64m x 64oc:
// acc[2][2] f32x16 = 64 AGPR. 32 sub-buffers x 9 phases x 4 MFMA.
__global__ __launch_bounds__(256, 3) void convlstm_main(
    const unsigned char* __restrict__ xh, const unsigned char* __restrict__ Wtb,
    const float* __restrict__ bh,  const float* __restrict__ cin,
    const float* __restrict__ Wci, const float* __restrict__ Wcf,
    const float* __restrict__ Wco, float* __restrict__ out)
{
    int bid = blockIdx.x;               // b*16 + nh*8 + cb
    int cb  = bid & 7;
    int nh  = (bid >> 3) & 1;
    int b   = bid >> 4;
    int tid = threadIdx.x;
    int lane = tid & 63, wv = tid >> 6;
    int l31 = lane & 31, hl = lane >> 5;

    __shared__ __align__(16) unsigned char lds[2][10368];

    // accumulators init with bias bh[oc]
    f32x16 acc[2][2];
#pragma unroll
    for (int f = 0; f < 2; ++f) {
        int fg = nh*2 + f;
        f32x16 v;
#pragma unroll
        for (int r = 0; r < 16; ++r) {
            int gate = r & 3, q = r >> 2;
            v[r] = bh[gate*256 + cb*32 + fg*8 + 2*q + hl];
        }
        acc[0][f] = v; acc[1][f] = v;
    }

    const unsigned char* subs = xh + (size_t)b * (32u * SUB_B);

// Stage one 10368-B sub-plane: waves 0-2 take 3 KB each, wave 3 takes the
// last 1 KB + masked 128-B tail (8 lanes).
#define STAGE(BUF, SRC)                                                      \
    if (wv < 3) {                                                            \
        _Pragma("unroll")                                                    \
        for (int j = 0; j < 3; ++j)                                          \
            gload_lds16((SRC) + (size_t)(wv*3072 + j*1024 + lane*16),        \
                        &lds[BUF][wv*3072 + j*1024 + lane*16]);              \
    } else {                                                                 \
        gload_lds16((SRC) + (size_t)(9216 + lane*16),                        \
                    &lds[BUF][9216 + lane*16]);                              \
        if (lane < 8)                                                        \
            gload_lds16((SRC) + (size_t)(10240 + lane*16),                   \
                        &lds[BUF][10240 + lane*16]);                         \
    }

    // initial stage: sub-buffer 0 into LDS buffer 0
    STAGE(0, subs)

    // B address bases: m0 = wv*64 + l31 (m1 = m0+32 -> p+36).
    // byte(p) = (p*32 + hl*16 + buf*10368) ^ ((p&4)<<2); addr1 = (addr0+1152)^16.
    int m0 = wv*64 + l31;
    int pbase0 = (m0 >> 4)*18 + (m0 & 15);
    uint32_t pk0 = (uint32_t)pbase0*32u + (uint32_t)(hl*16);
    const char* ldsbase = (const char*)&lds[0][0];

    // A pointer: uniform base + lane*16; per-phase offsets literal.
    const unsigned char* wptr = Wtb + (size_t)(cb*2 + nh)*589824u
                                    + (size_t)(lane*16);
    const unsigned char* srcn = subs + SUB_B;   // next sub-plane to stage

    bf16x8 A[2][2], Bb[2][2];
    // A prologue: (sub0, p0) into A[0]
    A[0][0] = *(const bf16x8*)(wptr + 0);
    A[0][1] = *(const bf16x8*)(wptr + 1024);

    __syncthreads();   // initial DMA drained (full), waves joined

// One sub-buffer. PAR literal 0/1: LDS buffer = PAR, ping = (p+PAR)&1.
// p8 A-prefetch (tp=9 -> wptr+18432 = next sub) goes to A[PAR^1]; next
// sub-buffer (parity PAR^1) consumes p0 from A[PAR^1]. LASTF gates DMA.
#define SUBBUF(PAR, LASTF)                                                   \
    {                                                                        \
        {   /* B prologue: pos 0, dist-0 (data valid only after barrier) */  \
            uint32_t p0a = (pk0 + (PAR)*10368u)                              \
                           ^ (((uint32_t)pbase0 & 4u) << 2);                 \
            uint32_t p1a = (p0a + 1152u) ^ 16u;                              \
            Bb[(PAR)][0] = *(const bf16x8*)(ldsbase + p0a);                  \
            Bb[(PAR)][1] = *(const bf16x8*)(ldsbase + p1a);                  \
        }                                                                    \
        _Pragma("unroll")                                                    \
        for (int p = 0; p < 9; ++p) {                                        \
            const int ping = (p + (PAR)) & 1;                                \
            {   /* A prefetch dist-1 (tp==9 reads next sub-buffer) */        \
                const int aoff = (p + 1) * 2048;                             \
                A[ping ^ 1][0] = *(const bf16x8*)(wptr + aoff);              \
                A[ping ^ 1][1] = *(const bf16x8*)(wptr + aoff + 1024);       \
            }                                                                \
            if (p == 1 && !(LASTF)) { STAGE((PAR) ^ 1, srcn) }               \
            if (p < 8) {   /* B prefetch dist-1 */                           \
                const int np = p + 1;                                        \
                const uint32_t D = (uint32_t)((np/3)*18 + (np%3));           \
                uint32_t pp = (uint32_t)pbase0 + D;                          \
                uint32_t a0 = (pk0 + D*32u + (PAR)*10368u)                   \
                              ^ ((pp & 4u) << 2);                            \
                uint32_t a1 = (a0 + 1152u) ^ 16u;                            \
                Bb[ping ^ 1][0] = *(const bf16x8*)(ldsbase + a0);            \
                Bb[ping ^ 1][1] = *(const bf16x8*)(ldsbase + a1);            \
            }                                                                \
            __builtin_amdgcn_s_setprio(1);                                   \
            acc[0][0] = __builtin_amdgcn_mfma_f32_32x32x16_bf16(A[ping][0], Bb[ping][0], acc[0][0], 0, 0, 0); \
            acc[0][1] = __builtin_amdgcn_mfma_f32_32x32x16_bf16(A[ping][1], Bb[ping][0], acc[0][1], 0, 0, 0); \
            acc[1][0] = __builtin_amdgcn_mfma_f32_32x32x16_bf16(A[ping][0], Bb[ping][1], acc[1][0], 0, 0, 0); \
            acc[1][1] = __builtin_amdgcn_mfma_f32_32x32x16_bf16(A[ping][1], Bb[ping][1], acc[1][1], 0, 0, 0); \
            __builtin_amdgcn_s_setprio(0);                                   \
        }                                                                    \
        wptr += 18432;                                                       \
        srcn += SUB_B;                                                       \
        /* counted barrier: 4 newest vmem (p7/p8 A prefetches) in flight; */ \
        /* DMA + older A loads complete. */                                  \
        asm volatile("s_waitcnt vmcnt(4) lgkmcnt(0)" ::: "memory");          \
        __builtin_amdgcn_s_barrier();                                        \
        __builtin_amdgcn_sched_barrier(0);                                   \
    }

    for (int sb2 = 0; sb2 < 16; ++sb2) {
        SUBBUF(0, false)
        SUBBUF(1, (sb2 == 15))
    }
#undef SUBBUF
#undef STAGE

    // fused LSTM epilogue. col = l31 (m), r = 4*q + gate,
    // ch = cb*32 + fg*8 + 2*q + hl.
    float* outh = out;
    float* outc = out + (size_t)OUT_HALF;
    const size_t bOff = (size_t)b * (256*256);
#pragma unroll
    for (int mf = 0; mf < 2; ++mf) {
        int m = wv*64 + mf*32 + l31;
#pragma unroll
        for (int f = 0; f < 2; ++f) {
            int fg = nh*2 + f;
#pragma unroll
            for (int q = 0; q < 4; ++q) {
                int ch = cb*32 + fg*8 + 2*q + hl;
                size_t pidx = (size_t)ch*256 + (size_t)m;
                size_t idx  = bOff + pidx;
                float cv = cin[idx];
                float pi = acc[mf][f][4*q+0];
                float pf = acc[mf][f][4*q+1];
                float pc = acc[mf][f][4*q+2];
                float po = acc[mf][f][4*q+3];
                float it = 1.f/(1.f + __expf(-(pi + Wci[pidx]*cv)));
                float ft = 1.f/(1.f + __expf(-(pf + Wcf[pidx]*cv)));
                float tc = 1.f - 2.f/(1.f + __expf(2.f*pc));
                float ct = ft*cv + it*tc;
                float ot = 1.f/(1.f + __expf(-(po + Wco[pidx]*ct)));
                float th = 1.f - 2.f/(1.f + __expf(2.f*ct));
                outh[idx] = ot*th;
                outc[idx] = ct;
            }
        }
    }
}

// ---------------------------------------------------------------------------
extern "C" void kernel_launch(void* const* d_in, const int* in_sizes, int n_in,
                              void* d_out, int out_size, void* d_ws, size_t ws_size,
                              hipStream_t stream)
{
    const float* x   = (const float*)d_in[0];
    const float* h   = (const float*)d_in[1];
    const float* c   = (const float*)d_in[2];
    const float* Wx  = (const float*)d_in[3];
    const float* Wh  = (const float*)d_in[4];
    const float* bh  = (const float*)d_in[5];
    const float* Wci = (const float*)d_in[6];
    const float* Wcf = (const float*)d_in[7];
    const float* Wco = (const float*)d_in[8];
    float* out = (float*)d_out;

    // Wt FIRST so the final sub-buffer's dummy A prefetch overrun lands in
    // the xh region (valid memory).
    unsigned char* wtb = (unsigned char*)d_ws;       // 9.44 MB
    unsigned char* xh  = wtb + (size_t)WT_BYTES;     // 8192 x 10368 B

    hipLaunchKernelGGL(xh_transform, dim3(4096), dim3(256), 0, stream, x, h, xh);
    hipLaunchKernelGGL(w_transform,  dim3(2304), dim3(256), 0, stream,
                       Wx, Wh, (__bf16*)wtb);
    hipLaunchKernelGGL(convlstm_main, dim3(4096), dim3(256), 0, stream,
                       xh, wtb, bh, c, Wci, Wcf, Wco, out);
}